// Round 9
// baseline (497.460 us; speedup 1.0000x reference)
//
#include <hip/hip_runtime.h>

#define I_DIM 32
#define J_DIM 32
#define S_DIM 256
#define H_DIM 768
#define KC    32                  // f16 elems per K-chunk
#define NCH   (H_DIM / KC)        // 24 chunks
#define TILE_B 32768              // 256 rows x 128 B (h|l slots, XOR-swizzled)
#define WSQ_BYTES ((size_t)I_DIM * NCH * TILE_B)   // 24 MB
#define WSK_BYTES ((size_t)J_DIM * NCH * TILE_B)   // 24 MB

typedef _Float16 f16x8 __attribute__((ext_vector_type(8)));
typedef float    f32x16 __attribute__((ext_vector_type(16)));

static __device__ __forceinline__ unsigned short f16bits(_Float16 h) {
    union { _Float16 f; unsigned short u; } cv; cv.f = h; return cv.u;
}

// ---------------------------------------------------------------------------
// Pre-pass: one wave per row. Normalize, split fp16 hi + fp16 residual, store
// in pre-swizzled LDS tile image: row s occupies 128 B; 16B slot for k-group
// kg (hi: kg, lo: kg^4 -> addr^64), slot index XOR (s&7).
// ---------------------------------------------------------------------------
__global__ __launch_bounds__(256) void li_split_kernel(
    const float* __restrict__ qe, const float* __restrict__ ke,
    char* __restrict__ wsQ, char* __restrict__ wsK)
{
    const int lane = threadIdx.x & 63;
    const int w    = threadIdx.x >> 6;
    const int r    = blockIdx.x * 4 + w;               // 0..16383
    const bool isQ = r < I_DIM * S_DIM;
    const int row  = isQ ? r : r - I_DIM * S_DIM;
    const float* base = (isQ ? qe : ke) + (size_t)row * H_DIM;

    float4 v[3];
    v[0] = *(const float4*)(base + 4 * lane);
    v[1] = *(const float4*)(base + 4 * lane + 256);
    v[2] = *(const float4*)(base + 4 * lane + 512);
    float ss = 0.0f;
    #pragma unroll
    for (int g = 0; g < 3; ++g)
        ss += v[g].x * v[g].x + v[g].y * v[g].y + v[g].z * v[g].z + v[g].w * v[g].w;
    #pragma unroll
    for (int m = 1; m < 64; m <<= 1) ss += __shfl_xor(ss, m, 64);
    const float inv = 1.0f / fmaxf(sqrtf(ss), 1e-12f);

    const int mi  = row >> 8;
    const int s   = row & 255;
    const int r7  = s & 7;
    char* wsb = (isQ ? wsQ : wsK) + (size_t)mi * NCH * TILE_B + s * 128;

    #pragma unroll
    for (int g = 0; g < 3; ++g) {
        const int k0 = 4 * lane + 256 * g;
        const int c  = k0 >> 5;
        const int kk = k0 & 31;
        float xn[4] = {v[g].x * inv, v[g].y * inv, v[g].z * inv, v[g].w * inv};
        unsigned short hb[4], lb[4];
        #pragma unroll
        for (int e = 0; e < 4; ++e) {
            _Float16 h  = (_Float16)xn[e];
            _Float16 lo = (_Float16)(xn[e] - (float)h);
            hb[e] = f16bits(h);
            lb[e] = f16bits(lo);
        }
        char* p = wsb + (size_t)c * TILE_B + (((kk >> 3) ^ r7) << 4) + (kk & 7) * 2;
        *(uint2*)(p)        = make_uint2(hb[0] | ((unsigned)hb[1] << 16), hb[2] | ((unsigned)hb[3] << 16));
        *(uint2*)((char*)((size_t)p ^ 64)) = make_uint2(lb[0] | ((unsigned)lb[1] << 16), lb[2] | ((unsigned)lb[3] << 16));
    }
}

// ---------------------------------------------------------------------------
// Main: 512 threads = 8 waves (4 wy x 2 wx); wave owns 64 rows x 128 cols.
// m201-style 4-phase chunk schedule: each phase = {2 gll prefetch + ds_read
// burst} -> s_barrier -> lgkmcnt(0) -> setprio(1) 12 MFMA setprio(0) ->
// s_barrier. Counted vmcnt(2) once per chunk (P0). Dbuf LDS.
// ---------------------------------------------------------------------------
__global__ __launch_bounds__(512, 2) void li_mfma_kernel(
    const char* __restrict__ wsQ, const char* __restrict__ wsK,
    const float* __restrict__ qm, const float* __restrict__ km,
    const float* __restrict__ alpha_raw, float* __restrict__ out)
{
    __shared__ __align__(16) char sQ[2][TILE_B];
    __shared__ __align__(16) char sK[2][TILE_B];
    __shared__ float kmsh[256], qmsh[256];
    __shared__ float pm[256][2], pL[256][2], pW[256][2];
    __shared__ float redA[512], redB[512];

    const int tid = threadIdx.x;
    const int wid = tid >> 6;
    const int l   = tid & 63;
    const int l31 = l & 31;
    const int hi  = l >> 5;
    const int wx  = wid & 1;    // col half (128 cols)
    const int wy  = wid >> 1;   // row quarter (64 rows)
    const int r7  = l31 & 7;

    // XCD-aware: XCD x hosts j in {4x..4x+3} -> K_j stays L2-resident
    const int bidx = blockIdx.x;
    const int x  = bidx & 7;
    const int r0 = bidx >> 3;
    const int j  = x * 4 + (r0 & 3);
    const int i  = r0 >> 2;

    if (tid < 256) {
        kmsh[tid] = km[j * 256 + tid];
        qmsh[tid] = qm[i * 256 + tid];
    }
    const float araw  = alpha_raw[0];
    const float alpha = (araw > 20.0f) ? araw : log1pf(expf(araw));
    const float nal   = -alpha;

    const char* qbase = wsQ + (size_t)i * NCH * TILE_B;
    const char* kbase = wsK + (size_t)j * NCH * TILE_B;

    f32x16 acc[2][4];
    #pragma unroll
    for (int mr = 0; mr < 2; ++mr)
        #pragma unroll
        for (int nt = 0; nt < 4; ++nt)
            #pragma unroll
            for (int z = 0; z < 16; ++z) acc[mr][nt][z] = 0.0f;

    // per-wave LDS sub-block offset for staging
    const int sgo = wid * 4096 + l * 16;

#define GLL2(buf, c, u)                                                                   \
    do {                                                                                  \
        __builtin_amdgcn_global_load_lds(                                                 \
            (const __attribute__((address_space(1))) void*)                               \
                (qbase + (size_t)(c) * TILE_B + sgo + (u) * 1024),                        \
            (__attribute__((address_space(3))) void*)(sQ[buf] + wid * 4096 + (u) * 1024), \
            16, 0, 0);                                                                    \
        __builtin_amdgcn_global_load_lds(                                                 \
            (const __attribute__((address_space(1))) void*)                               \
                (kbase + (size_t)(c) * TILE_B + sgo + (u) * 1024),                        \
            (__attribute__((address_space(3))) void*)(sK[buf] + wid * 4096 + (u) * 1024), \
            16, 0, 0);                                                                    \
    } while (0)

#define SB() __builtin_amdgcn_sched_barrier(0)
#define BAR() do { SB(); __builtin_amdgcn_s_barrier(); SB(); } while (0)
#define LGKM0() do { asm volatile("s_waitcnt lgkmcnt(0)" ::: "memory"); SB(); } while (0)
#define MFMA1(A, B, C) __builtin_amdgcn_mfma_f32_32x32x16_f16(A, B, C, 0, 0, 0)

// 12 MFMAs for column pair (na, nb) using held Q regs
#define MFMA12(KHa, KLa, KHb, KLb, na, nb)                          \
    do {                                                            \
        __builtin_amdgcn_s_setprio(1);                              \
        acc[0][na] = MFMA1(qh0, KHa, acc[0][na]);                   \
        acc[0][nb] = MFMA1(qh0, KHb, acc[0][nb]);                   \
        acc[1][na] = MFMA1(qh1, KHa, acc[1][na]);                   \
        acc[1][nb] = MFMA1(qh1, KHb, acc[1][nb]);                   \
        acc[0][na] = MFMA1(qh0, KLa, acc[0][na]);                   \
        acc[0][nb] = MFMA1(qh0, KLb, acc[0][nb]);                   \
        acc[1][na] = MFMA1(qh1, KLa, acc[1][na]);                   \
        acc[1][nb] = MFMA1(qh1, KLb, acc[1][nb]);                   \
        acc[0][na] = MFMA1(ql0, KHa, acc[0][na]);                   \
        acc[0][nb] = MFMA1(ql0, KHb, acc[0][nb]);                   \
        acc[1][na] = MFMA1(ql1, KHa, acc[1][na]);                   \
        acc[1][nb] = MFMA1(ql1, KHb, acc[1][nb]);                   \
        __builtin_amdgcn_s_setprio(0);                              \
    } while (0)

    const int rqA = (wy * 64 + l31) * 128;         // Q row A byte offset
    const int rqB = rqA + 32 * 128;                // Q row B
    const int rk0 = (wx * 128 + l31) * 128;        // K col base (nt=0)

    // prologue: stage chunk 0 fully, drain, sync
    GLL2(0, 0, 0); GLL2(0, 0, 1); GLL2(0, 0, 2); GLL2(0, 0, 3);
    asm volatile("s_waitcnt vmcnt(0)" ::: "memory");
    BAR();

    for (int c = 0; c < NCH; ++c) {
        const char* bQ = sQ[c & 1];
        const char* bK = sK[c & 1];
        const int nb = (c + 1) & 1;
        const bool pf = (c + 1 < NCH);

        f16x8 qh0, ql0, qh1, ql1;
        f16x8 kh_a, kl_a, kh_b, kl_b;

        // ================= ks = 0 =================
        {
            const int soff = (hi ^ r7) << 4;           // (0*2+hi)^r7
            // ---- P0: prefetch u0, vmcnt(2), bar, dsread 8, lgkm0, MFMA 12, bar
            if (pf) {
                GLL2(nb, c + 1, 0);
                asm volatile("s_waitcnt vmcnt(2)" ::: "memory");
            } else {
                asm volatile("s_waitcnt vmcnt(0)" ::: "memory");
            }
            BAR();
            qh0 = *(const f16x8*)(bQ + rqA + soff);
            ql0 = *(const f16x8*)(bQ + ((rqA + soff) ^ 64));
            qh1 = *(const f16x8*)(bQ + rqB + soff);
            ql1 = *(const f16x8*)(bQ + ((rqB + soff) ^ 64));
            kh_a = *(const f16x8*)(bK + rk0 + soff);
            kl_a = *(const f16x8*)(bK + ((rk0 + soff) ^ 64));
            kh_b = *(const f16x8*)(bK + rk0 + 32 * 128 + soff);
            kl_b = *(const f16x8*)(bK + ((rk0 + 32 * 128 + soff) ^ 64));
            LGKM0();
            MFMA12(kh_a, kl_a, kh_b, kl_b, 0, 1);
            BAR();
            // ---- P1: prefetch u1, dsread 4 (nt2,3), bar, lgkm0, MFMA 12, bar
            if (pf) GLL2(nb, c + 1, 1);
            kh_a = *(const f16x8*)(bK + rk0 + 64 * 128 + soff);
            kl_a = *(const f16x8*)(bK + ((rk0 + 64 * 128 + soff) ^ 64));
            kh_b = *(const f16x8*)(bK + rk0 + 96 * 128 + soff);
            kl_b = *(const f16x8*)(bK + ((rk0 + 96 * 128 + soff) ^ 64));
            BAR();
            LGKM0();
            MFMA12(kh_a, kl_a, kh_b, kl_b, 2, 3);
            BAR();
        }
        // ================= ks = 1 =================
        {
            const int soff = ((2 + hi) ^ r7) << 4;     // (1*2+hi)^r7
            // ---- P2
            if (pf) GLL2(nb, c + 1, 2);
            qh0 = *(const f16x8*)(bQ + rqA + soff);
            ql0 = *(const f16x8*)(bQ + ((rqA + soff) ^ 64));
            qh1 = *(const f16x8*)(bQ + rqB + soff);
            ql1 = *(const f16x8*)(bQ + ((rqB + soff) ^ 64));
            kh_a = *(const f16x8*)(bK + rk0 + soff);
            kl_a = *(const f16x8*)(bK + ((rk0 + soff) ^ 64));
            kh_b = *(const f16x8*)(bK + rk0 + 32 * 128 + soff);
            kl_b = *(const f16x8*)(bK + ((rk0 + 32 * 128 + soff) ^ 64));
            BAR();
            LGKM0();
            MFMA12(kh_a, kl_a, kh_b, kl_b, 0, 1);
            BAR();
            // ---- P3
            if (pf) GLL2(nb, c + 1, 3);
            kh_a = *(const f16x8*)(bK + rk0 + 64 * 128 + soff);
            kl_a = *(const f16x8*)(bK + ((rk0 + 64 * 128 + soff) ^ 64));
            kh_b = *(const f16x8*)(bK + rk0 + 96 * 128 + soff);
            kl_b = *(const f16x8*)(bK + ((rk0 + 96 * 128 + soff) ^ 64));
            BAR();
            LGKM0();
            MFMA12(kh_a, kl_a, kh_b, kl_b, 2, 3);
            BAR();
        }
    }
#undef GLL2
#undef MFMA12
#undef MFMA1

    // ---- per-wave softmax partials over its 128-col half ----
    #pragma unroll
    for (int mrep = 0; mrep < 2; ++mrep) {
        #pragma unroll
        for (int reg = 0; reg < 16; ++reg) {
            const int srow = wy * 64 + mrep * 32 + hi * 4 + (reg & 3) + 8 * (reg >> 2);
            const float qms = qmsh[srow];
            float mv[4], cvv[4];
            float mloc = -3.0e38f;
            #pragma unroll
            for (int nt = 0; nt < 4; ++nt) {
                const int tcol = wx * 128 + nt * 32 + l31;
                const float cv = acc[mrep][nt][reg];
                int dd = srow - tcol; dd = dd < 0 ? -dd : dd;
                const float valid = qms * kmsh[tcol];
                const float m = cv * __expf(nal * (float)dd) * valid - (1.0f - valid) * 1e9f;
                mv[nt] = m; cvv[nt] = cv;
                mloc = fmaxf(mloc, m);
            }
            #pragma unroll
            for (int mm = 1; mm < 32; mm <<= 1)
                mloc = fmaxf(mloc, __shfl_xor(mloc, mm, 32));
            float L = 0.0f, W = 0.0f;
            #pragma unroll
            for (int nt = 0; nt < 4; ++nt) {
                const float e = __expf(mv[nt] - mloc);
                L += e;
                W += e * cvv[nt];
            }
            #pragma unroll
            for (int mm = 1; mm < 32; mm <<= 1) {
                L += __shfl_xor(L, mm, 32);
                W += __shfl_xor(W, mm, 32);
            }
            if (l31 == 0) {
                pm[srow][wx] = mloc;
                pL[srow][wx] = L;
                pW[srow][wx] = W;
            }
        }
    }
    __syncthreads();

    // ---- merge col-halves per row, then block-reduce ----
    float contrib = 0.0f, qq = 0.0f;
    if (tid < 256) {
        const float m0 = pm[tid][0], m1 = pm[tid][1];
        const float M  = fmaxf(m0, m1);
        const float e0 = __expf(m0 - M), e1 = __expf(m1 - M);
        const float L  = pL[tid][0] * e0 + pL[tid][1] * e1;
        const float W  = pW[tid][0] * e0 + pW[tid][1] * e1;
        contrib = (W / L) * qmsh[tid];
        qq = qmsh[tid];
    }
    redA[tid] = contrib;
    redB[tid] = qq;
    __syncthreads();
    for (int off = 256; off > 0; off >>= 1) {
        if (tid < off) {
            redA[tid] += redA[tid + off];
            redB[tid] += redB[tid + off];
        }
        __syncthreads();
    }
    if (tid == 0) out[i * 32 + j] = redA[0] / fmaxf(redB[0], 1.0f);
}

// ---------------------------------------------------------------------------
extern "C" void kernel_launch(void* const* d_in, const int* in_sizes, int n_in,
                              void* d_out, int out_size, void* d_ws, size_t ws_size,
                              hipStream_t stream)
{
    const float* qe = (const float*)d_in[0];
    const float* ke = (const float*)d_in[1];
    const float* qm = (const float*)d_in[2];
    const float* km = (const float*)d_in[3];
    const float* al = (const float*)d_in[4];
    float* out = (float*)d_out;

    char* wsQ = (char*)d_ws;
    char* wsK = wsQ + WSQ_BYTES;

    hipLaunchKernelGGL(li_split_kernel, dim3((I_DIM + J_DIM) * S_DIM / 4), dim3(256),
                       0, stream, qe, ke, wsQ, wsK);
    hipLaunchKernelGGL(li_mfma_kernel, dim3(I_DIM * J_DIM), dim3(512), 0, stream,
                       wsQ, wsK, qm, km, al, out);
}